// Round 15
// baseline (381.160 us; speedup 1.0000x reference)
//
#include <hip/hip_runtime.h>

#define N_NODES 20000
#define N_EDGES 640000
#define D 128
#define H 128

#define EB    64                 // edges per tile (edge kernel)
#define TPB   256                // 4 waves (edge kernel)
#define NBLK4 1024               // edge blocks (4/CU), strided tile schedule
#define NTILE (N_EDGES / EB)     // 10000
#define EBN   64                 // rows per tile (node/uvp kernels)
#define NNT64 ((N_NODES + EBN - 1) / EBN)  // 313
#define NSCAT ((N_EDGES + 255) / 256)      // 2500 scatter blocks
#define ST    136                // bf16 tile row stride; 272B % 128 = 16

// ---- workspace layout (bytes) ----
#define WS_W1   0                // We1[:, :256] bf16 [128][256]
#define WS_W2   65536            // We2 bf16 [128][128]
#define WS_WC1  98304            // Wc1 bf16 [128][128]
#define WS_WN1  131072           // Wn1 bf16 [128][256]
#define WS_WN2  196608           // Wn2 bf16 [128][128]
#define WS_CNT  229376           // int[20000]
#define WS_CUR  309376           // int[20000]
#define WS_PERM 389376           // int[640000]
#define WS_U    2949376          // u bf16 [20000][128]
#define WS_V    8069376          // v bf16 [20000][128]
#define WS_P    13189376         // p bf16 [20000][128]

typedef short bf16x8 __attribute__((ext_vector_type(8)));
typedef float f32x4  __attribute__((ext_vector_type(4)));

__device__ __forceinline__ float silu_f(float x) {
    return x * __builtin_amdgcn_rcpf(1.0f + __expf(-x));
}
__device__ __forceinline__ ushort f2b(float f) {          // f32 -> bf16 RNE (scalar)
    union { float f; unsigned int u; } v; v.f = f;
    return (ushort)((v.u + 0x7FFF + ((v.u >> 16) & 1)) >> 16);
}
__device__ __forceinline__ float b2f(ushort s) {
    union { unsigned int u; float f; } v; v.u = ((unsigned int)s) << 16; return v.f;
}
// packed f32 pair -> 2xbf16 in one u32 (HW RNE)
__device__ __forceinline__ unsigned f2b2(float lo, float hi) {
    unsigned r;
    asm("v_cvt_pk_bf16_f32 %0, %1, %2" : "=v"(r) : "v"(lo), "v"(hi));
    return r;
}

// LDS-only barrier: orders ds ops across the workgroup but does NOT drain
// vmcnt — register-destined global loads stay in flight across it.
__device__ __forceinline__ void bar_lds() {
    asm volatile("s_waitcnt lgkmcnt(0)" ::: "memory");
    __builtin_amdgcn_s_barrier();
    asm volatile("" ::: "memory");
}

// one K=32 chunk with register-resident B: acc[4][2] += A[64 x 32] @ Breg
// (edge kernel: 64-edge tile, eg == 0)
__device__ __forceinline__ void gemm_chunk_rw(const ushort* Ab, int kc0,
                                              const bf16x8 b[2], f32x4 acc[4][2],
                                              int eg, int lane)
{
    const int r = lane & 15, g = lane >> 4;
    bf16x8 a[4];
    #pragma unroll
    for (int mt = 0; mt < 4; ++mt)
        a[mt] = *(const bf16x8*)&Ab[(eg * 64 + mt * 16 + r) * ST + kc0 + g * 8];
    #pragma unroll
    for (int mt = 0; mt < 4; ++mt)
        #pragma unroll
        for (int nt = 0; nt < 2; ++nt)
            acc[mt][nt] = __builtin_amdgcn_mfma_f32_16x16x32_bf16(a[mt], b[nt], acc[mt][nt], 0, 0, 0);
}

__device__ __forceinline__ void zero_acc8(f32x4 acc[4][2]) {
    #pragma unroll
    for (int mt = 0; mt < 4; ++mt)
        #pragma unroll
        for (int nt = 0; nt < 2; ++nt)
            acc[mt][nt] = (f32x4){0.f, 0.f, 0.f, 0.f};
}

// pk-convert epilogue (edge kernel, eg==0)
__device__ __forceinline__ void epi_silu8_pk(f32x4 acc[4][2], const float* bias,
                                             ushort* out, int eg, int cg, int lane) {
    const int r = lane & 15, g = lane >> 4;
    #pragma unroll
    for (int nt = 0; nt < 2; ++nt) {
        int o = cg * 32 + nt * 16 + r;
        float bo = bias[o];
        #pragma unroll
        for (int mt = 0; mt < 4; ++mt) {
            int e = eg * 64 + mt * 16 + g * 4;
            unsigned p01 = f2b2(silu_f(acc[mt][nt][0] + bo), silu_f(acc[mt][nt][1] + bo));
            unsigned p23 = f2b2(silu_f(acc[mt][nt][2] + bo), silu_f(acc[mt][nt][3] + bo));
            out[(e + 0) * ST + o] = (ushort)p01;
            out[(e + 1) * ST + o] = (ushort)(p01 >> 16);
            out[(e + 2) * ST + o] = (ushort)p23;
            out[(e + 3) * ST + o] = (ushort)(p23 >> 16);
        }
    }
}

// ---------------- prep: weight bf16 conversion + cout copy + histogram + hout zero ----------------
__global__ void prep2(const float* __restrict__ We1, const float* __restrict__ We2,
                      const float* __restrict__ Wc1, const float* __restrict__ Wn1,
                      const float* __restrict__ Wn2, const float* __restrict__ coordp,
                      const int* __restrict__ eidx,
                      ushort* w1, ushort* w2, ushort* wc1, ushort* wn1, ushort* wn2,
                      float* cout, int* cnt, float* hout)
{
    int idx = blockIdx.x * 256 + threadIdx.x;
    if (idx < N_EDGES) {
        // hout zero: 640000 threads x float4 == N_NODES*D floats exactly
        *(float4*)&hout[(size_t)idx * 4] = (float4){0.f, 0.f, 0.f, 0.f};
        atomicAdd(&cnt[eidx[idx]], 1);
    }
    int j = idx;
    if (j < 32768) { w1[j] = f2b(We1[(j >> 8) * 257 + (j & 255)]); return; }
    j -= 32768;
    if (j < 16384) { w2[j] = f2b(We2[j]); return; }
    j -= 16384;
    if (j < 16384) { wc1[j] = f2b(Wc1[j]); return; }
    j -= 16384;
    if (j < 32768) { wn1[j] = f2b(Wn1[j]); return; }
    j -= 32768;
    if (j < 16384) { wn2[j] = f2b(Wn2[j]); return; }
    j -= 16384;
    if (j < N_NODES * 3) cout[j] = coordp[j];
}

// ---------------- counting sort: exclusive scan ----------------
__global__ void scan_k(const int* __restrict__ cnt, int* cur) {
    __shared__ int wsum[16];
    __shared__ int carry_s;
    const int t = threadIdx.x, lane = t & 63, wid = t >> 6;
    if (t == 0) carry_s = 0;
    __syncthreads();
    for (int base = 0; base < N_NODES; base += 1024) {
        int i = base + t;
        int vv = (i < N_NODES) ? cnt[i] : 0;
        int s = vv;
        #pragma unroll
        for (int d = 1; d < 64; d <<= 1) {
            int x = __shfl_up(s, d);
            if (lane >= d) s += x;
        }
        if (lane == 63) wsum[wid] = s;
        __syncthreads();
        if (wid == 0) {
            int ws = (lane < 16) ? wsum[lane] : 0;
            #pragma unroll
            for (int d = 1; d < 16; d <<= 1) {
                int x = __shfl_up(ws, d);
                if (lane >= d) ws += x;
            }
            if (lane < 16) wsum[lane] = ws;
        }
        __syncthreads();
        int woff = (wid > 0) ? wsum[wid - 1] : 0;
        if (i < N_NODES) cur[i] = carry_s + woff + s - vv;
        __syncthreads();
        if (t == 0) carry_s += wsum[15];
        __syncthreads();
    }
}

// ---------------- merged: uvp precompute (blocks < NNT64) + sort scatter ----------------
__global__ __launch_bounds__(256, 2)
void uvp_scatter_k(const float* __restrict__ h,
                   const ushort* __restrict__ w1b, const ushort* __restrict__ wn1b,
                   const float* __restrict__ be1, const float* __restrict__ bn1,
                   ushort* __restrict__ u, ushort* __restrict__ v, ushort* __restrict__ p,
                   const int* __restrict__ eidx, int* cur, int* perm)
{
    const int tid = threadIdx.x;
    if (blockIdx.x >= NNT64) {              // ---- scatter part ----
        int e = (blockIdx.x - NNT64) * 256 + tid;
        if (e < N_EDGES) {
            int pp = atomicAdd(&cur[eidx[e]], 1);
            perm[pp] = e;
        }
        return;
    }
    // ---- uvp part ----
    __shared__ __align__(16) ushort hs[EBN * ST];
    __shared__ float b1s[H], bn1s[H];

    const int lane = tid & 63, wv = tid >> 6;
    const int eg = wv >> 2, cg = wv & 3;
    const int r = lane & 15, g = lane >> 4;
    const int n0 = blockIdx.x * EBN;

    if (tid < 128) b1s[tid] = be1[tid];
    else if (tid < 256) bn1s[tid - 128] = bn1[tid - 128];

    bf16x8 wa[4][2], wb[4][2], wn[4][2];
    {
        const int c0 = cg * 32 + r, c1c = c0 + 16;
        #pragma unroll
        for (int kc = 0; kc < 4; ++kc) {
            wa[kc][0] = *(const bf16x8*)&w1b [c0  * 256 +       kc * 32 + g * 8];
            wa[kc][1] = *(const bf16x8*)&w1b [c1c * 256 +       kc * 32 + g * 8];
            wb[kc][0] = *(const bf16x8*)&w1b [c0  * 256 + 128 + kc * 32 + g * 8];
            wb[kc][1] = *(const bf16x8*)&w1b [c1c * 256 + 128 + kc * 32 + g * 8];
            wn[kc][0] = *(const bf16x8*)&wn1b[c0  * 256 +       kc * 32 + g * 8];
            wn[kc][1] = *(const bf16x8*)&wn1b[c1c * 256 +       kc * 32 + g * 8];
        }
    }
    #pragma unroll
    for (int it = 0; it < 8; ++it) {
        int idx = tid + it * 256;
        int e = idx >> 5, c = idx & 31;
        int n = n0 + e; if (n >= N_NODES) n = 0;
        float4 vv = *(const float4*)&h[(size_t)n * D + c * 4];
        ushort4 pk; pk.x = f2b(vv.x); pk.y = f2b(vv.y); pk.z = f2b(vv.z); pk.w = f2b(vv.w);
        *(ushort4*)&hs[e * ST + c * 4] = pk;
    }
    __syncthreads();

    f32x4 acc[4][2];
    zero_acc8(acc);
    #pragma unroll
    for (int kc = 0; kc < 4; ++kc) gemm_chunk_rw(hs, kc * 32, wa[kc], acc, 0, lane);
    #pragma unroll
    for (int nt = 0; nt < 2; ++nt) {
        int o = cg * 32 + nt * 16 + r;
        float bo = b1s[o];
        #pragma unroll
        for (int mt = 0; mt < 4; ++mt)
            #pragma unroll
            for (int j = 0; j < 4; ++j) {
                int n = n0 + mt * 16 + g * 4 + j;
                if (n < N_NODES) u[(size_t)n * H + o] = f2b(acc[mt][nt][j] + bo);
            }
    }
    zero_acc8(acc);
    #pragma unroll
    for (int kc = 0; kc < 4; ++kc) gemm_chunk_rw(hs, kc * 32, wb[kc], acc, 0, lane);
    #pragma unroll
    for (int nt = 0; nt < 2; ++nt) {
        int o = cg * 32 + nt * 16 + r;
        #pragma unroll
        for (int mt = 0; mt < 4; ++mt)
            #pragma unroll
            for (int j = 0; j < 4; ++j) {
                int n = n0 + mt * 16 + g * 4 + j;
                if (n < N_NODES) v[(size_t)n * H + o] = f2b(acc[mt][nt][j]);
            }
    }
    zero_acc8(acc);
    #pragma unroll
    for (int kc = 0; kc < 4; ++kc) gemm_chunk_rw(hs, kc * 32, wn[kc], acc, 0, lane);
    #pragma unroll
    for (int nt = 0; nt < 2; ++nt) {
        int o = cg * 32 + nt * 16 + r;
        float bo = bn1s[o];
        #pragma unroll
        for (int mt = 0; mt < 4; ++mt)
            #pragma unroll
            for (int j = 0; j < 4; ++j) {
                int n = n0 + mt * 16 + g * 4 + j;
                if (n < N_NODES) p[(size_t)n * H + o] = f2b(acc[mt][nt][j] + bo);
            }
    }
}

// ---------------- fused edge kernel (64-edge tiles, 4 blocks/CU) ----------------
__global__ __launch_bounds__(TPB, 4)
void egcl_edge(const ushort* __restrict__ u, const ushort* __restrict__ v,
               const int* __restrict__ eidx, const int* __restrict__ perm,
               const float* __restrict__ coordp,
               const ushort* __restrict__ w2b, const ushort* __restrict__ wc1b,
               const float* __restrict__ We1,
               const float* __restrict__ be2, const float* __restrict__ bc1,
               const float* __restrict__ Wc2,
               float* __restrict__ agg, float* __restrict__ coord_out)
{
    __shared__ __align__(16) ushort t1[EB * ST];          // 17408 B
    __shared__ __align__(16) ushort ef[EB * ST];          // 17408 B
    __shared__ int   srcs_s[2][EB];                       // 512 B
    __shared__ int   dsts_s[EB];                          // 256 B (single buffer)
    __shared__ float radial_s[2][EB];                     // 512 B
    __shared__ float cdx_s[2][EB], cdy_s[2][EB], cdz_s[2][EB]; // 1536 B
    __shared__ float wcop[4][EB];                         // 1024 B
    __shared__ float b2s[H], bc1s[H], wc2s[H], w256s[H];  // 2048 B  => total 40704 B

    const int tid = threadIdx.x, lane = tid & 63;
    const int cg = tid >> 6;                   // 4 waves = 4 col groups
    const int r = lane & 15, g = lane >> 4;
    const int ce = tid >> 2, cq = tid & 3;     // commit/reduce mapping (64 edges x 4)

    if (tid < 128) { b2s[tid] = be2[tid];  wc2s[tid] = Wc2[tid]; }
    else { int o = tid - 128; bc1s[o] = bc1[o]; w256s[o] = We1[o * 257 + 256]; }

    bf16x8 w2f[4][2], w3f[4][2];
    {
        const int c0 = cg * 32 + r, c1c = c0 + 16;
        #pragma unroll
        for (int kc = 0; kc < 4; ++kc) {
            w2f[kc][0] = *(const bf16x8*)&w2b [c0  * 128 + kc * 32 + g * 8];
            w2f[kc][1] = *(const bf16x8*)&w2b [c1c * 128 + kc * 32 + g * 8];
            w3f[kc][0] = *(const bf16x8*)&wc1b[c0  * 128 + kc * 32 + g * 8];
            w3f[kc][1] = *(const bf16x8*)&wc1b[c1c * 128 + kc * 32 + g * 8];
        }
    }

    // ---- prologue ----
    int t = (int)blockIdx.x;                  // strided: t, t+NBLK4, ...
    int rs = 0, rd = 0;
    float rsx = 0, rsy = 0, rsz = 0, rdx = 0, rdy = 0, rdz = 0;
    if (tid < EB) {
        int e = perm[t * EB + tid];
        int s = eidx[e], d = eidx[N_EDGES + e];
        srcs_s[0][tid] = s; dsts_s[tid] = d;
        float sx = coordp[s * 3], sy = coordp[s * 3 + 1], sz = coordp[s * 3 + 2];
        float dx0 = coordp[d * 3], dy0 = coordp[d * 3 + 1], dz0 = coordp[d * 3 + 2];
        float dx = sx - dx0, dy = sy - dy0, dz = sz - dz0;
        cdx_s[0][tid] = dx; cdy_s[0][tid] = dy; cdz_s[0][tid] = dz;
        radial_s[0][tid] = dx * dx + dy * dy + dz * dz;
    }
    __syncthreads();

    bf16x8 uvr[8];
    {
        const ushort* up = u + (size_t)srcs_s[0][ce] * H + cq * 32;
        const ushort* vp = v + (size_t)dsts_s[ce] * H + cq * 32;
        #pragma unroll
        for (int i = 0; i < 4; ++i) {
            uvr[i]     = *(const bf16x8*)(up + i * 8);
            uvr[4 + i] = *(const bf16x8*)(vp + i * 8);
        }
    }
    if (tid < EB && t + NBLK4 < NTILE) {
        int e = perm[(t + NBLK4) * EB + tid];
        rs = eidx[e]; rd = eidx[N_EDGES + e];
        rsx = coordp[rs * 3]; rsy = coordp[rs * 3 + 1]; rsz = coordp[rs * 3 + 2];
        rdx = coordp[rd * 3]; rdy = coordp[rd * 3 + 1]; rdz = coordp[rd * 3 + 2];
    }

    f32x4 acc[4][2];
    int pb = 0;

    for (; t < NTILE; t += NBLK4) {
        // ---- p0: commit uvr -> t1 = silu(u+v+radial*w256); commit chain -> idx[pb^1]
        {
            float rad = radial_s[pb][ce];
            #pragma unroll
            for (int i = 0; i < 4; ++i) {
                float4 wlo = *(const float4*)&w256s[cq * 32 + i * 8];
                float4 whi = *(const float4*)&w256s[cq * 32 + i * 8 + 4];
                bf16x8 uu = uvr[i], vx = uvr[4 + i];
                float x0 = silu_f(b2f((ushort)uu[0]) + b2f((ushort)vx[0]) + rad * wlo.x);
                float x1 = silu_f(b2f((ushort)uu[1]) + b2f((ushort)vx[1]) + rad * wlo.y);
                float x2 = silu_f(b2f((ushort)uu[2]) + b2f((ushort)vx[2]) + rad * wlo.z);
                float x3 = silu_f(b2f((ushort)uu[3]) + b2f((ushort)vx[3]) + rad * wlo.w);
                float x4 = silu_f(b2f((ushort)uu[4]) + b2f((ushort)vx[4]) + rad * whi.x);
                float x5 = silu_f(b2f((ushort)uu[5]) + b2f((ushort)vx[5]) + rad * whi.y);
                float x6 = silu_f(b2f((ushort)uu[6]) + b2f((ushort)vx[6]) + rad * whi.z);
                float x7 = silu_f(b2f((ushort)uu[7]) + b2f((ushort)vx[7]) + rad * whi.w);
                uint4 pk4;
                pk4.x = f2b2(x0, x1); pk4.y = f2b2(x2, x3);
                pk4.z = f2b2(x4, x5); pk4.w = f2b2(x6, x7);
                *(uint4*)&t1[ce * ST + cq * 32 + i * 8] = pk4;
            }
        }
        if (tid < EB) {
            srcs_s[pb ^ 1][tid] = rs; dsts_s[tid] = rd;
            float dx = rsx - rdx, dy = rsy - rdy, dz = rsz - rdz;
            cdx_s[pb ^ 1][tid] = dx; cdy_s[pb ^ 1][tid] = dy; cdz_s[pb ^ 1][tid] = dz;
            radial_s[pb ^ 1][tid] = dx * dx + dy * dy + dz * dz;
        }
        bar_lds();                                         // A: t1 + idx[pb^1] ready

        // ---- p1: uv(t+N) issue; perm(t+2N); GEMM2 t1 -> ef
        {
            const ushort* up = u + (size_t)srcs_s[pb ^ 1][ce] * H + cq * 32;
            const ushort* vp = v + (size_t)dsts_s[ce] * H + cq * 32;
            #pragma unroll
            for (int i = 0; i < 4; ++i) {
                uvr[i]     = *(const bf16x8*)(up + i * 8);
                uvr[4 + i] = *(const bf16x8*)(vp + i * 8);
            }
        }
        int en = 0;
        if (tid < EB && t + 2 * NBLK4 < NTILE) en = perm[(t + 2 * NBLK4) * EB + tid];
        zero_acc8(acc);
        __builtin_amdgcn_s_setprio(1);
        #pragma unroll
        for (int kc = 0; kc < 4; ++kc) gemm_chunk_rw(t1, kc * 32, w2f[kc], acc, 0, lane);
        __builtin_amdgcn_s_setprio(0);
        epi_silu8_pk(acc, b2s, ef, 0, cg, lane);
        bar_lds();                                         // B: ef ready

        // ---- p2: eidx(t+2N); GEMM3 swapped (W as A, ef as B) -> fused wco; agg scatter
        int rs2 = 0, rd2 = 0;
        if (tid < EB) { rs2 = eidx[en]; rd2 = eidx[N_EDGES + en]; }
        {
            f32x4 acc3[2][4];
            #pragma unroll
            for (int ot = 0; ot < 2; ++ot)
                #pragma unroll
                for (int et = 0; et < 4; ++et)
                    acc3[ot][et] = (f32x4){0.f, 0.f, 0.f, 0.f};
            __builtin_amdgcn_s_setprio(1);
            #pragma unroll
            for (int kc = 0; kc < 4; ++kc) {
                bf16x8 bfr[4];
                #pragma unroll
                for (int et = 0; et < 4; ++et)
                    bfr[et] = *(const bf16x8*)&ef[(et * 16 + r) * ST + kc * 32 + g * 8];
                #pragma unroll
                for (int ot = 0; ot < 2; ++ot)
                    #pragma unroll
                    for (int et = 0; et < 4; ++et)
                        acc3[ot][et] = __builtin_amdgcn_mfma_f32_16x16x32_bf16(
                            w3f[kc][ot], bfr[et], acc3[ot][et], 0, 0, 0);
            }
            __builtin_amdgcn_s_setprio(0);
            // fused epilogue: partial[et] = sum_o silu(acc3+bc1[o]) * wc2[o]
            float partial[4] = {0.f, 0.f, 0.f, 0.f};
            #pragma unroll
            for (int ot = 0; ot < 2; ++ot) {
                int ob = cg * 32 + ot * 16 + g * 4;
                float4 wq = *(const float4*)&wc2s[ob];
                float4 bq = *(const float4*)&bc1s[ob];
                #pragma unroll
                for (int et = 0; et < 4; ++et) {
                    partial[et] += silu_f(acc3[ot][et][0] + bq.x) * wq.x
                                 + silu_f(acc3[ot][et][1] + bq.y) * wq.y
                                 + silu_f(acc3[ot][et][2] + bq.z) * wq.z
                                 + silu_f(acc3[ot][et][3] + bq.w) * wq.w;
                }
            }
            #pragma unroll
            for (int et = 0; et < 4; ++et) {
                float s_ = partial[et];
                s_ += __shfl_xor(s_, 16);
                s_ += __shfl_xor(s_, 32);
                if (g == 0) wcop[cg][et * 16 + r] = s_;
            }
        }
        {   // segmented agg scatter (reads ef, ready since barrier B)
            int o = tid & 127, q = tid >> 7;   // 2 quarters x 32 edges
            int base = q * 32;
            float sum = 0.f;
            int curs = srcs_s[pb][base];
            for (int k = 0; k < 32; ++k) {
                int e = base + k;
                int s = srcs_s[pb][e];
                if (s != curs) {
                    atomicAdd(&agg[(size_t)curs * D + o], sum);
                    sum = 0.f; curs = s;
                }
                sum += b2f(ef[e * ST + o]);
            }
            atomicAdd(&agg[(size_t)curs * D + o], sum);
        }
        bar_lds();                                         // C: wcop ready

        // ---- p3: coord(t+2N) chain; wco sum + coord scatter
        if (tid < EB) {
            rs = rs2; rd = rd2;
            rsx = coordp[rs * 3]; rsy = coordp[rs * 3 + 1]; rsz = coordp[rs * 3 + 2];
            rdx = coordp[rd * 3]; rdy = coordp[rd * 3 + 1]; rdz = coordp[rd * 3 + 2];
        }
        {
            float s_ = wcop[cq][ce];
            s_ += __shfl_down(s_, 2);
            s_ += __shfl_down(s_, 1);
            float wfull = __shfl(s_, lane & ~3);
            if (cq < 3) {
                float cdv = (cq == 0) ? cdx_s[pb][ce] : (cq == 1) ? cdy_s[pb][ce] : cdz_s[pb][ce];
                atomicAdd(&coord_out[(size_t)srcs_s[pb][ce] * 3 + cq], cdv * wfull);
            }
        }
        bar_lds();                                         // E: buffers reusable
        pb ^= 1;
    }
}

// ---------------- node kernel: h_out = h + Wn2 @ silu(p + agg@Wn1b^T) + bn2 ----
__global__ __launch_bounds__(256, 4)
void egcl_node(const float* __restrict__ h,
               const ushort* __restrict__ wn1b, const ushort* __restrict__ wn2b,
               const ushort* __restrict__ pArr, const float* __restrict__ bn2,
               float* __restrict__ hout /* holds agg on entry */)
{
    __shared__ __align__(16) ushort t1[EBN * ST];
    __shared__ __align__(16) ushort t2[EBN * ST];
    __shared__ float b2s[H];

    const int tid = threadIdx.x, lane = tid & 63, wv = tid >> 6;
    const int cg = wv & 3;
    const int r = lane & 15, g = lane >> 4;
    const int n0 = blockIdx.x * EBN;

    if (tid < 128) b2s[tid] = bn2[tid];

    bf16x8 wnb[4][2], w2f[4][2];
    {
        const int c0 = cg * 32 + r, c1c = c0 + 16;
        #pragma unroll
        for (int kc = 0; kc < 4; ++kc) {
            wnb[kc][0] = *(const bf16x8*)&wn1b[c0  * 256 + 128 + kc * 32 + g * 8];
            wnb[kc][1] = *(const bf16x8*)&wn1b[c1c * 256 + 128 + kc * 32 + g * 8];
            w2f[kc][0] = *(const bf16x8*)&wn2b[c0  * 128 + kc * 32 + g * 8];
            w2f[kc][1] = *(const bf16x8*)&wn2b[c1c * 128 + kc * 32 + g * 8];
        }
    }
    #pragma unroll
    for (int it = 0; it < 8; ++it) {
        int idx = tid + it * 256;
        int e = idx >> 5, c = idx & 31;
        int n = n0 + e; if (n >= N_NODES) n = 0;
        float4 vv = *(const float4*)&hout[(size_t)n * D + c * 4];
        ushort4 pk; pk.x = f2b(vv.x); pk.y = f2b(vv.y); pk.z = f2b(vv.z); pk.w = f2b(vv.w);
        *(ushort4*)&t1[e * ST + c * 4] = pk;
    }
    __syncthreads();

    f32x4 acc[4][2];
    zero_acc8(acc);
    #pragma unroll
    for (int kc = 0; kc < 4; ++kc) gemm_chunk_rw(t1, kc * 32, wnb[kc], acc, 0, lane);
    #pragma unroll
    for (int nt = 0; nt < 2; ++nt) {
        int o = cg * 32 + nt * 16 + r;
        #pragma unroll
        for (int mt = 0; mt < 4; ++mt)
            #pragma unroll
            for (int j = 0; j < 4; ++j) {
                int e = mt * 16 + g * 4 + j;
                int n = n0 + e; if (n >= N_NODES) n = 0;
                float x = acc[mt][nt][j] + b2f(pArr[(size_t)n * H + o]);
                t2[e * ST + o] = f2b(silu_f(x));
            }
    }
    __syncthreads();

    zero_acc8(acc);
    #pragma unroll
    for (int kc = 0; kc < 4; ++kc) gemm_chunk_rw(t2, kc * 32, w2f[kc], acc, 0, lane);
    #pragma unroll
    for (int nt = 0; nt < 2; ++nt) {
        int o = cg * 32 + nt * 16 + r;
        float bo = b2s[o];
        #pragma unroll
        for (int mt = 0; mt < 4; ++mt)
            #pragma unroll
            for (int j = 0; j < 4; ++j) {
                int n = n0 + mt * 16 + g * 4 + j;
                if (n < N_NODES)
                    hout[(size_t)n * D + o] = h[(size_t)n * D + o] + acc[mt][nt][j] + bo;
            }
    }
}

extern "C" void kernel_launch(void* const* d_in, const int* in_sizes, int n_in,
                              void* d_out, int out_size, void* d_ws, size_t ws_size,
                              hipStream_t stream)
{
    const float* h     = (const float*)d_in[0];
    const float* coord = (const float*)d_in[1];
    const int*   eidx  = (const int*)d_in[2];
    const float* We1 = (const float*)d_in[3];
    const float* be1 = (const float*)d_in[4];
    const float* We2 = (const float*)d_in[5];
    const float* be2 = (const float*)d_in[6];
    const float* Wn1 = (const float*)d_in[7];
    const float* bn1 = (const float*)d_in[8];
    const float* Wn2 = (const float*)d_in[9];
    const float* bn2 = (const float*)d_in[10];
    const float* Wc1 = (const float*)d_in[11];
    const float* bc1 = (const float*)d_in[12];
    const float* Wc2 = (const float*)d_in[13];

    float* hout = (float*)d_out;                       // h_out; doubles as agg accumulator
    float* cout = (float*)d_out + (size_t)N_NODES * D; // coord_out

    char* ws = (char*)d_ws;
    ushort* w1b  = (ushort*)(ws + WS_W1);
    ushort* w2b  = (ushort*)(ws + WS_W2);
    ushort* wc1b = (ushort*)(ws + WS_WC1);
    ushort* wn1b = (ushort*)(ws + WS_WN1);
    ushort* wn2b = (ushort*)(ws + WS_WN2);
    int* cnt  = (int*)(ws + WS_CNT);
    int* cur  = (int*)(ws + WS_CUR);
    int* perm = (int*)(ws + WS_PERM);
    ushort* uArr = (ushort*)(ws + WS_U);
    ushort* vArr = (ushort*)(ws + WS_V);
    ushort* pArr = (ushort*)(ws + WS_P);

    hipMemsetAsync(cnt, 0, N_NODES * sizeof(int), stream);
    prep2<<<(N_EDGES + 255) / 256, 256, 0, stream>>>(We1, We2, Wc1, Wn1, Wn2, coord, eidx,
                                                     w1b, w2b, wc1b, wn1b, wn2b, cout, cnt, hout);
    scan_k<<<1, 1024, 0, stream>>>(cnt, cur);
    uvp_scatter_k<<<NNT64 + NSCAT, 256, 0, stream>>>(
        h, w1b, wn1b, be1, bn1, uArr, vArr, pArr, eidx, cur, perm);
    egcl_edge<<<NBLK4, TPB, 0, stream>>>(uArr, vArr, eidx, perm, coord,
                                         w2b, wc1b, We1, be2, bc1, Wc2,
                                         hout, cout);
    egcl_node<<<NNT64, 256, 0, stream>>>(h, wn1b, wn2b, pArr, bn2, hout);
}

// Round 16
// 307.579 us; speedup vs baseline: 1.2392x; 1.2392x over previous
//
#include <hip/hip_runtime.h>

#define N_NODES 20000
#define N_EDGES 640000
#define D 128
#define H 128

#define EB    64                 // edges per tile (edge kernel)
#define TPB   256                // 4 waves (edge kernel)
#define NBLK4 1024               // edge blocks (4/CU), strided tile schedule
#define NTILE (N_EDGES / EB)     // 10000
#define EBN   64                 // rows per tile (node/uvp kernels)
#define NNT64 ((N_NODES + EBN - 1) / EBN)  // 313
#define NSCAT ((N_EDGES + 255) / 256)      // 2500 scatter blocks
#define ST    136                // bf16 tile row stride; 272B % 128 = 16

// ---- workspace layout (bytes) ----
#define WS_W1   0                // We1[:, :256] bf16 [128][256]
#define WS_W2   65536            // We2 bf16 [128][128]
#define WS_WC1  98304            // Wc1 bf16 [128][128]
#define WS_WN1  131072           // Wn1 bf16 [128][256]
#define WS_WN2  196608           // Wn2 bf16 [128][128]
#define WS_CNT  229376           // int[20000]
#define WS_CUR  309376           // int[20000]
#define WS_PERM 389376           // int[640000]
#define WS_U    2949376          // u bf16 [20000][128]
#define WS_V    8069376          // v bf16 [20000][128]
#define WS_P    13189376         // p bf16 [20000][128]

typedef short bf16x8 __attribute__((ext_vector_type(8)));
typedef float f32x4  __attribute__((ext_vector_type(4)));

__device__ __forceinline__ float silu_f(float x) {
    return x * __builtin_amdgcn_rcpf(1.0f + __expf(-x));
}
__device__ __forceinline__ ushort f2b(float f) {          // f32 -> bf16 RNE (scalar)
    union { float f; unsigned int u; } v; v.f = f;
    return (ushort)((v.u + 0x7FFF + ((v.u >> 16) & 1)) >> 16);
}
__device__ __forceinline__ float b2f(ushort s) {
    union { unsigned int u; float f; } v; v.u = ((unsigned int)s) << 16; return v.f;
}
// packed f32 pair -> 2xbf16 in one u32 (HW RNE)
__device__ __forceinline__ unsigned f2b2(float lo, float hi) {
    unsigned r;
    asm("v_cvt_pk_bf16_f32 %0, %1, %2" : "=v"(r) : "v"(lo), "v"(hi));
    return r;
}

// LDS-only barrier: orders ds ops across the workgroup but does NOT drain
// vmcnt — register-destined global loads stay in flight across it.
__device__ __forceinline__ void bar_lds() {
    asm volatile("s_waitcnt lgkmcnt(0)" ::: "memory");
    __builtin_amdgcn_s_barrier();
    asm volatile("" ::: "memory");
}

// one K=32 chunk with register-resident B: acc[4][2] += A[64 x 32] @ Breg
__device__ __forceinline__ void gemm_chunk_rw(const ushort* Ab, int kc0,
                                              const bf16x8 b[2], f32x4 acc[4][2],
                                              int eg, int lane)
{
    const int r = lane & 15, g = lane >> 4;
    bf16x8 a[4];
    #pragma unroll
    for (int mt = 0; mt < 4; ++mt)
        a[mt] = *(const bf16x8*)&Ab[(eg * 64 + mt * 16 + r) * ST + kc0 + g * 8];
    #pragma unroll
    for (int mt = 0; mt < 4; ++mt)
        #pragma unroll
        for (int nt = 0; nt < 2; ++nt)
            acc[mt][nt] = __builtin_amdgcn_mfma_f32_16x16x32_bf16(a[mt], b[nt], acc[mt][nt], 0, 0, 0);
}

__device__ __forceinline__ void zero_acc8(f32x4 acc[4][2]) {
    #pragma unroll
    for (int mt = 0; mt < 4; ++mt)
        #pragma unroll
        for (int nt = 0; nt < 2; ++nt)
            acc[mt][nt] = (f32x4){0.f, 0.f, 0.f, 0.f};
}

// pk-convert epilogue (edge kernel, eg==0)
__device__ __forceinline__ void epi_silu8_pk(f32x4 acc[4][2], const float* bias,
                                             ushort* out, int eg, int cg, int lane) {
    const int r = lane & 15, g = lane >> 4;
    #pragma unroll
    for (int nt = 0; nt < 2; ++nt) {
        int o = cg * 32 + nt * 16 + r;
        float bo = bias[o];
        #pragma unroll
        for (int mt = 0; mt < 4; ++mt) {
            int e = eg * 64 + mt * 16 + g * 4;
            unsigned p01 = f2b2(silu_f(acc[mt][nt][0] + bo), silu_f(acc[mt][nt][1] + bo));
            unsigned p23 = f2b2(silu_f(acc[mt][nt][2] + bo), silu_f(acc[mt][nt][3] + bo));
            out[(e + 0) * ST + o] = (ushort)p01;
            out[(e + 1) * ST + o] = (ushort)(p01 >> 16);
            out[(e + 2) * ST + o] = (ushort)p23;
            out[(e + 3) * ST + o] = (ushort)(p23 >> 16);
        }
    }
}

// ---------------- prep: weight bf16 conversion + cout copy + histogram + hout zero ----------------
__global__ void prep2(const float* __restrict__ We1, const float* __restrict__ We2,
                      const float* __restrict__ Wc1, const float* __restrict__ Wn1,
                      const float* __restrict__ Wn2, const float* __restrict__ coordp,
                      const int* __restrict__ eidx,
                      ushort* w1, ushort* w2, ushort* wc1, ushort* wn1, ushort* wn2,
                      float* cout, int* cnt, float* hout)
{
    int idx = blockIdx.x * 256 + threadIdx.x;
    if (idx < N_EDGES) {
        // hout zero: 640000 threads x float4 == N_NODES*D floats exactly
        *(float4*)&hout[(size_t)idx * 4] = (float4){0.f, 0.f, 0.f, 0.f};
        atomicAdd(&cnt[eidx[idx]], 1);
    }
    int j = idx;
    if (j < 32768) { w1[j] = f2b(We1[(j >> 8) * 257 + (j & 255)]); return; }
    j -= 32768;
    if (j < 16384) { w2[j] = f2b(We2[j]); return; }
    j -= 16384;
    if (j < 16384) { wc1[j] = f2b(Wc1[j]); return; }
    j -= 16384;
    if (j < 32768) { wn1[j] = f2b(Wn1[j]); return; }
    j -= 32768;
    if (j < 16384) { wn2[j] = f2b(Wn2[j]); return; }
    j -= 16384;
    if (j < N_NODES * 3) cout[j] = coordp[j];
}

// ---------------- counting sort: exclusive scan ----------------
__global__ void scan_k(const int* __restrict__ cnt, int* cur) {
    __shared__ int wsum[16];
    __shared__ int carry_s;
    const int t = threadIdx.x, lane = t & 63, wid = t >> 6;
    if (t == 0) carry_s = 0;
    __syncthreads();
    for (int base = 0; base < N_NODES; base += 1024) {
        int i = base + t;
        int vv = (i < N_NODES) ? cnt[i] : 0;
        int s = vv;
        #pragma unroll
        for (int d = 1; d < 64; d <<= 1) {
            int x = __shfl_up(s, d);
            if (lane >= d) s += x;
        }
        if (lane == 63) wsum[wid] = s;
        __syncthreads();
        if (wid == 0) {
            int ws = (lane < 16) ? wsum[lane] : 0;
            #pragma unroll
            for (int d = 1; d < 16; d <<= 1) {
                int x = __shfl_up(ws, d);
                if (lane >= d) ws += x;
            }
            if (lane < 16) wsum[lane] = ws;
        }
        __syncthreads();
        int woff = (wid > 0) ? wsum[wid - 1] : 0;
        if (i < N_NODES) cur[i] = carry_s + woff + s - vv;
        __syncthreads();
        if (t == 0) carry_s += wsum[15];
        __syncthreads();
    }
}

// ---------------- merged: uvp precompute (blocks < NNT64) + sort scatter ----------------
__global__ __launch_bounds__(256, 2)
void uvp_scatter_k(const float* __restrict__ h,
                   const ushort* __restrict__ w1b, const ushort* __restrict__ wn1b,
                   const float* __restrict__ be1, const float* __restrict__ bn1,
                   ushort* __restrict__ u, ushort* __restrict__ v, ushort* __restrict__ p,
                   const int* __restrict__ eidx, int* cur, int* perm)
{
    const int tid = threadIdx.x;
    if (blockIdx.x >= NNT64) {              // ---- scatter part ----
        int e = (blockIdx.x - NNT64) * 256 + tid;
        if (e < N_EDGES) {
            int pp = atomicAdd(&cur[eidx[e]], 1);
            perm[pp] = e;
        }
        return;
    }
    // ---- uvp part ----
    __shared__ __align__(16) ushort hs[EBN * ST];
    __shared__ float b1s[H], bn1s[H];

    const int lane = tid & 63, wv = tid >> 6;
    const int cg = wv & 3;
    const int r = lane & 15, g = lane >> 4;
    const int n0 = blockIdx.x * EBN;

    if (tid < 128) b1s[tid] = be1[tid];
    else if (tid < 256) bn1s[tid - 128] = bn1[tid - 128];

    bf16x8 wa[4][2], wb[4][2], wn[4][2];
    {
        const int c0 = cg * 32 + r, c1c = c0 + 16;
        #pragma unroll
        for (int kc = 0; kc < 4; ++kc) {
            wa[kc][0] = *(const bf16x8*)&w1b [c0  * 256 +       kc * 32 + g * 8];
            wa[kc][1] = *(const bf16x8*)&w1b [c1c * 256 +       kc * 32 + g * 8];
            wb[kc][0] = *(const bf16x8*)&w1b [c0  * 256 + 128 + kc * 32 + g * 8];
            wb[kc][1] = *(const bf16x8*)&w1b [c1c * 256 + 128 + kc * 32 + g * 8];
            wn[kc][0] = *(const bf16x8*)&wn1b[c0  * 256 +       kc * 32 + g * 8];
            wn[kc][1] = *(const bf16x8*)&wn1b[c1c * 256 +       kc * 32 + g * 8];
        }
    }
    #pragma unroll
    for (int it = 0; it < 8; ++it) {
        int idx = tid + it * 256;
        int e = idx >> 5, c = idx & 31;
        int n = n0 + e; if (n >= N_NODES) n = 0;
        float4 vv = *(const float4*)&h[(size_t)n * D + c * 4];
        ushort4 pk; pk.x = f2b(vv.x); pk.y = f2b(vv.y); pk.z = f2b(vv.z); pk.w = f2b(vv.w);
        *(ushort4*)&hs[e * ST + c * 4] = pk;
    }
    __syncthreads();

    f32x4 acc[4][2];
    zero_acc8(acc);
    #pragma unroll
    for (int kc = 0; kc < 4; ++kc) gemm_chunk_rw(hs, kc * 32, wa[kc], acc, 0, lane);
    #pragma unroll
    for (int nt = 0; nt < 2; ++nt) {
        int o = cg * 32 + nt * 16 + r;
        float bo = b1s[o];
        #pragma unroll
        for (int mt = 0; mt < 4; ++mt)
            #pragma unroll
            for (int j = 0; j < 4; ++j) {
                int n = n0 + mt * 16 + g * 4 + j;
                if (n < N_NODES) u[(size_t)n * H + o] = f2b(acc[mt][nt][j] + bo);
            }
    }
    zero_acc8(acc);
    #pragma unroll
    for (int kc = 0; kc < 4; ++kc) gemm_chunk_rw(hs, kc * 32, wb[kc], acc, 0, lane);
    #pragma unroll
    for (int nt = 0; nt < 2; ++nt) {
        int o = cg * 32 + nt * 16 + r;
        #pragma unroll
        for (int mt = 0; mt < 4; ++mt)
            #pragma unroll
            for (int j = 0; j < 4; ++j) {
                int n = n0 + mt * 16 + g * 4 + j;
                if (n < N_NODES) v[(size_t)n * H + o] = f2b(acc[mt][nt][j]);
            }
    }
    zero_acc8(acc);
    #pragma unroll
    for (int kc = 0; kc < 4; ++kc) gemm_chunk_rw(hs, kc * 32, wn[kc], acc, 0, lane);
    #pragma unroll
    for (int nt = 0; nt < 2; ++nt) {
        int o = cg * 32 + nt * 16 + r;
        float bo = bn1s[o];
        #pragma unroll
        for (int mt = 0; mt < 4; ++mt)
            #pragma unroll
            for (int j = 0; j < 4; ++j) {
                int n = n0 + mt * 16 + g * 4 + j;
                if (n < N_NODES) p[(size_t)n * H + o] = f2b(acc[mt][nt][j] + bo);
            }
    }
}

// ---------------- fused edge kernel (64-edge tiles, 4 blocks/CU, VGPR cap 128) ----------------
// launch_bounds 2nd arg empirical rule on this hipcc: cap = 256/arg VGPRs
// (arg=4 -> 64-reg cap -> spills; arg=2 -> 128-reg cap, fits ~108 live set).
// Occupancy here is LDS-limited: 4 x 40704 B <= 160 KiB -> 4 blocks/CU.
__global__ __launch_bounds__(TPB, 2)
void egcl_edge(const ushort* __restrict__ u, const ushort* __restrict__ v,
               const int* __restrict__ eidx, const int* __restrict__ perm,
               const float* __restrict__ coordp,
               const ushort* __restrict__ w2b, const ushort* __restrict__ wc1b,
               const float* __restrict__ We1,
               const float* __restrict__ be2, const float* __restrict__ bc1,
               const float* __restrict__ Wc2,
               float* __restrict__ agg, float* __restrict__ coord_out)
{
    __shared__ __align__(16) ushort t1[EB * ST];          // 17408 B
    __shared__ __align__(16) ushort ef[EB * ST];          // 17408 B
    __shared__ int   srcs_s[2][EB];                       // 512 B
    __shared__ int   dsts_s[EB];                          // 256 B (single buffer)
    __shared__ float radial_s[2][EB];                     // 512 B
    __shared__ float cdx_s[2][EB], cdy_s[2][EB], cdz_s[2][EB]; // 1536 B
    __shared__ float wcop[4][EB];                         // 1024 B
    __shared__ float b2s[H], bc1s[H], wc2s[H], w256s[H];  // 2048 B  => total 40704 B

    const int tid = threadIdx.x, lane = tid & 63;
    const int cg = tid >> 6;                   // 4 waves = 4 col groups
    const int r = lane & 15, g = lane >> 4;
    const int ce = tid >> 2, cq = tid & 3;     // commit/reduce mapping (64 edges x 4)

    if (tid < 128) { b2s[tid] = be2[tid];  wc2s[tid] = Wc2[tid]; }
    else { int o = tid - 128; bc1s[o] = bc1[o]; w256s[o] = We1[o * 257 + 256]; }

    bf16x8 w2f[4][2], w3f[4][2];
    {
        const int c0 = cg * 32 + r, c1c = c0 + 16;
        #pragma unroll
        for (int kc = 0; kc < 4; ++kc) {
            w2f[kc][0] = *(const bf16x8*)&w2b [c0  * 128 + kc * 32 + g * 8];
            w2f[kc][1] = *(const bf16x8*)&w2b [c1c * 128 + kc * 32 + g * 8];
            w3f[kc][0] = *(const bf16x8*)&wc1b[c0  * 128 + kc * 32 + g * 8];
            w3f[kc][1] = *(const bf16x8*)&wc1b[c1c * 128 + kc * 32 + g * 8];
        }
    }

    // ---- prologue ----
    int t = (int)blockIdx.x;                  // strided: t, t+NBLK4, ...
    int rs = 0, rd = 0;
    float rsx = 0, rsy = 0, rsz = 0, rdx = 0, rdy = 0, rdz = 0;
    if (tid < EB) {
        int e = perm[t * EB + tid];
        int s = eidx[e], d = eidx[N_EDGES + e];
        srcs_s[0][tid] = s; dsts_s[tid] = d;
        float sx = coordp[s * 3], sy = coordp[s * 3 + 1], sz = coordp[s * 3 + 2];
        float dx0 = coordp[d * 3], dy0 = coordp[d * 3 + 1], dz0 = coordp[d * 3 + 2];
        float dx = sx - dx0, dy = sy - dy0, dz = sz - dz0;
        cdx_s[0][tid] = dx; cdy_s[0][tid] = dy; cdz_s[0][tid] = dz;
        radial_s[0][tid] = dx * dx + dy * dy + dz * dz;
    }
    __syncthreads();

    bf16x8 uvr[8];
    {
        const ushort* up = u + (size_t)srcs_s[0][ce] * H + cq * 32;
        const ushort* vp = v + (size_t)dsts_s[ce] * H + cq * 32;
        #pragma unroll
        for (int i = 0; i < 4; ++i) {
            uvr[i]     = *(const bf16x8*)(up + i * 8);
            uvr[4 + i] = *(const bf16x8*)(vp + i * 8);
        }
    }
    if (tid < EB && t + NBLK4 < NTILE) {
        int e = perm[(t + NBLK4) * EB + tid];
        rs = eidx[e]; rd = eidx[N_EDGES + e];
        rsx = coordp[rs * 3]; rsy = coordp[rs * 3 + 1]; rsz = coordp[rs * 3 + 2];
        rdx = coordp[rd * 3]; rdy = coordp[rd * 3 + 1]; rdz = coordp[rd * 3 + 2];
    }

    f32x4 acc[4][2];
    int pb = 0;

    for (; t < NTILE; t += NBLK4) {
        // ---- p0: commit uvr -> t1 = silu(u+v+radial*w256); commit chain -> idx[pb^1]
        {
            float rad = radial_s[pb][ce];
            #pragma unroll
            for (int i = 0; i < 4; ++i) {
                float4 wlo = *(const float4*)&w256s[cq * 32 + i * 8];
                float4 whi = *(const float4*)&w256s[cq * 32 + i * 8 + 4];
                bf16x8 uu = uvr[i], vx = uvr[4 + i];
                float x0 = silu_f(b2f((ushort)uu[0]) + b2f((ushort)vx[0]) + rad * wlo.x);
                float x1 = silu_f(b2f((ushort)uu[1]) + b2f((ushort)vx[1]) + rad * wlo.y);
                float x2 = silu_f(b2f((ushort)uu[2]) + b2f((ushort)vx[2]) + rad * wlo.z);
                float x3 = silu_f(b2f((ushort)uu[3]) + b2f((ushort)vx[3]) + rad * wlo.w);
                float x4 = silu_f(b2f((ushort)uu[4]) + b2f((ushort)vx[4]) + rad * whi.x);
                float x5 = silu_f(b2f((ushort)uu[5]) + b2f((ushort)vx[5]) + rad * whi.y);
                float x6 = silu_f(b2f((ushort)uu[6]) + b2f((ushort)vx[6]) + rad * whi.z);
                float x7 = silu_f(b2f((ushort)uu[7]) + b2f((ushort)vx[7]) + rad * whi.w);
                uint4 pk4;
                pk4.x = f2b2(x0, x1); pk4.y = f2b2(x2, x3);
                pk4.z = f2b2(x4, x5); pk4.w = f2b2(x6, x7);
                *(uint4*)&t1[ce * ST + cq * 32 + i * 8] = pk4;
            }
        }
        if (tid < EB) {
            srcs_s[pb ^ 1][tid] = rs; dsts_s[tid] = rd;
            float dx = rsx - rdx, dy = rsy - rdy, dz = rsz - rdz;
            cdx_s[pb ^ 1][tid] = dx; cdy_s[pb ^ 1][tid] = dy; cdz_s[pb ^ 1][tid] = dz;
            radial_s[pb ^ 1][tid] = dx * dx + dy * dy + dz * dz;
        }
        bar_lds();                                         // A: t1 + idx[pb^1] ready

        // ---- p1: uv(t+N) issue; perm(t+2N); GEMM2 t1 -> ef
        {
            const ushort* up = u + (size_t)srcs_s[pb ^ 1][ce] * H + cq * 32;
            const ushort* vp = v + (size_t)dsts_s[ce] * H + cq * 32;
            #pragma unroll
            for (int i = 0; i < 4; ++i) {
                uvr[i]     = *(const bf16x8*)(up + i * 8);
                uvr[4 + i] = *(const bf16x8*)(vp + i * 8);
            }
        }
        int en = 0;
        if (tid < EB && t + 2 * NBLK4 < NTILE) en = perm[(t + 2 * NBLK4) * EB + tid];
        zero_acc8(acc);
        __builtin_amdgcn_s_setprio(1);
        #pragma unroll
        for (int kc = 0; kc < 4; ++kc) gemm_chunk_rw(t1, kc * 32, w2f[kc], acc, 0, lane);
        __builtin_amdgcn_s_setprio(0);
        epi_silu8_pk(acc, b2s, ef, 0, cg, lane);
        bar_lds();                                         // B: ef ready

        // ---- p2: eidx(t+2N); GEMM3 swapped (W as A, ef as B) -> fused wco; agg scatter
        int rs2 = 0, rd2 = 0;
        if (tid < EB) { rs2 = eidx[en]; rd2 = eidx[N_EDGES + en]; }
        {
            f32x4 acc3[2][4];
            #pragma unroll
            for (int ot = 0; ot < 2; ++ot)
                #pragma unroll
                for (int et = 0; et < 4; ++et)
                    acc3[ot][et] = (f32x4){0.f, 0.f, 0.f, 0.f};
            __builtin_amdgcn_s_setprio(1);
            #pragma unroll
            for (int kc = 0; kc < 4; ++kc) {
                bf16x8 bfr[4];
                #pragma unroll
                for (int et = 0; et < 4; ++et)
                    bfr[et] = *(const bf16x8*)&ef[(et * 16 + r) * ST + kc * 32 + g * 8];
                #pragma unroll
                for (int ot = 0; ot < 2; ++ot)
                    #pragma unroll
                    for (int et = 0; et < 4; ++et)
                        acc3[ot][et] = __builtin_amdgcn_mfma_f32_16x16x32_bf16(
                            w3f[kc][ot], bfr[et], acc3[ot][et], 0, 0, 0);
            }
            __builtin_amdgcn_s_setprio(0);
            // fused epilogue: partial[et] = sum_o silu(acc3+bc1[o]) * wc2[o]
            float partial[4] = {0.f, 0.f, 0.f, 0.f};
            #pragma unroll
            for (int ot = 0; ot < 2; ++ot) {
                int ob = cg * 32 + ot * 16 + g * 4;
                float4 wq = *(const float4*)&wc2s[ob];
                float4 bq = *(const float4*)&bc1s[ob];
                #pragma unroll
                for (int et = 0; et < 4; ++et) {
                    partial[et] += silu_f(acc3[ot][et][0] + bq.x) * wq.x
                                 + silu_f(acc3[ot][et][1] + bq.y) * wq.y
                                 + silu_f(acc3[ot][et][2] + bq.z) * wq.z
                                 + silu_f(acc3[ot][et][3] + bq.w) * wq.w;
                }
            }
            #pragma unroll
            for (int et = 0; et < 4; ++et) {
                float s_ = partial[et];
                s_ += __shfl_xor(s_, 16);
                s_ += __shfl_xor(s_, 32);
                if (g == 0) wcop[cg][et * 16 + r] = s_;
            }
        }
        {   // segmented agg scatter (reads ef, ready since barrier B)
            int o = tid & 127, q = tid >> 7;   // 2 quarters x 32 edges
            int base = q * 32;
            float sum = 0.f;
            int curs = srcs_s[pb][base];
            for (int k = 0; k < 32; ++k) {
                int e = base + k;
                int s = srcs_s[pb][e];
                if (s != curs) {
                    atomicAdd(&agg[(size_t)curs * D + o], sum);
                    sum = 0.f; curs = s;
                }
                sum += b2f(ef[e * ST + o]);
            }
            atomicAdd(&agg[(size_t)curs * D + o], sum);
        }
        bar_lds();                                         // C: wcop ready

        // ---- p3: coord(t+2N) chain; wco sum + coord scatter
        if (tid < EB) {
            rs = rs2; rd = rd2;
            rsx = coordp[rs * 3]; rsy = coordp[rs * 3 + 1]; rsz = coordp[rs * 3 + 2];
            rdx = coordp[rd * 3]; rdy = coordp[rd * 3 + 1]; rdz = coordp[rd * 3 + 2];
        }
        {
            float s_ = wcop[cq][ce];
            s_ += __shfl_down(s_, 2);
            s_ += __shfl_down(s_, 1);
            float wfull = __shfl(s_, lane & ~3);
            if (cq < 3) {
                float cdv = (cq == 0) ? cdx_s[pb][ce] : (cq == 1) ? cdy_s[pb][ce] : cdz_s[pb][ce];
                atomicAdd(&coord_out[(size_t)srcs_s[pb][ce] * 3 + cq], cdv * wfull);
            }
        }
        bar_lds();                                         // E: buffers reusable
        pb ^= 1;
    }
}

// ---------------- node kernel: h_out = h + Wn2 @ silu(p + agg@Wn1b^T) + bn2 ----
__global__ __launch_bounds__(256, 2)
void egcl_node(const float* __restrict__ h,
               const ushort* __restrict__ wn1b, const ushort* __restrict__ wn2b,
               const ushort* __restrict__ pArr, const float* __restrict__ bn2,
               float* __restrict__ hout /* holds agg on entry */)
{
    __shared__ __align__(16) ushort t1[EBN * ST];
    __shared__ __align__(16) ushort t2[EBN * ST];
    __shared__ float b2s[H];

    const int tid = threadIdx.x, lane = tid & 63, wv = tid >> 6;
    const int cg = wv & 3;
    const int r = lane & 15, g = lane >> 4;
    const int n0 = blockIdx.x * EBN;

    if (tid < 128) b2s[tid] = bn2[tid];

    bf16x8 wnb[4][2], w2f[4][2];
    {
        const int c0 = cg * 32 + r, c1c = c0 + 16;
        #pragma unroll
        for (int kc = 0; kc < 4; ++kc) {
            wnb[kc][0] = *(const bf16x8*)&wn1b[c0  * 256 + 128 + kc * 32 + g * 8];
            wnb[kc][1] = *(const bf16x8*)&wn1b[c1c * 256 + 128 + kc * 32 + g * 8];
            w2f[kc][0] = *(const bf16x8*)&wn2b[c0  * 128 + kc * 32 + g * 8];
            w2f[kc][1] = *(const bf16x8*)&wn2b[c1c * 128 + kc * 32 + g * 8];
        }
    }
    #pragma unroll
    for (int it = 0; it < 8; ++it) {
        int idx = tid + it * 256;
        int e = idx >> 5, c = idx & 31;
        int n = n0 + e; if (n >= N_NODES) n = 0;
        float4 vv = *(const float4*)&hout[(size_t)n * D + c * 4];
        ushort4 pk; pk.x = f2b(vv.x); pk.y = f2b(vv.y); pk.z = f2b(vv.z); pk.w = f2b(vv.w);
        *(ushort4*)&t1[e * ST + c * 4] = pk;
    }
    __syncthreads();

    f32x4 acc[4][2];
    zero_acc8(acc);
    #pragma unroll
    for (int kc = 0; kc < 4; ++kc) gemm_chunk_rw(t1, kc * 32, wnb[kc], acc, 0, lane);
    #pragma unroll
    for (int nt = 0; nt < 2; ++nt) {
        int o = cg * 32 + nt * 16 + r;
        #pragma unroll
        for (int mt = 0; mt < 4; ++mt)
            #pragma unroll
            for (int j = 0; j < 4; ++j) {
                int e = mt * 16 + g * 4 + j;
                int n = n0 + e; if (n >= N_NODES) n = 0;
                float x = acc[mt][nt][j] + b2f(pArr[(size_t)n * H + o]);
                t2[e * ST + o] = f2b(silu_f(x));
            }
    }
    __syncthreads();

    zero_acc8(acc);
    #pragma unroll
    for (int kc = 0; kc < 4; ++kc) gemm_chunk_rw(t2, kc * 32, w2f[kc], acc, 0, lane);
    #pragma unroll
    for (int nt = 0; nt < 2; ++nt) {
        int o = cg * 32 + nt * 16 + r;
        float bo = b2s[o];
        #pragma unroll
        for (int mt = 0; mt < 4; ++mt)
            #pragma unroll
            for (int j = 0; j < 4; ++j) {
                int n = n0 + mt * 16 + g * 4 + j;
                if (n < N_NODES)
                    hout[(size_t)n * D + o] = h[(size_t)n * D + o] + acc[mt][nt][j] + bo;
            }
    }
}

extern "C" void kernel_launch(void* const* d_in, const int* in_sizes, int n_in,
                              void* d_out, int out_size, void* d_ws, size_t ws_size,
                              hipStream_t stream)
{
    const float* h     = (const float*)d_in[0];
    const float* coord = (const float*)d_in[1];
    const int*   eidx  = (const int*)d_in[2];
    const float* We1 = (const float*)d_in[3];
    const float* be1 = (const float*)d_in[4];
    const float* We2 = (const float*)d_in[5];
    const float* be2 = (const float*)d_in[6];
    const float* Wn1 = (const float*)d_in[7];
    const float* bn1 = (const float*)d_in[8];
    const float* Wn2 = (const float*)d_in[9];
    const float* bn2 = (const float*)d_in[10];
    const float* Wc1 = (const float*)d_in[11];
    const float* bc1 = (const float*)d_in[12];
    const float* Wc2 = (const float*)d_in[13];

    float* hout = (float*)d_out;                       // h_out; doubles as agg accumulator
    float* cout = (float*)d_out + (size_t)N_NODES * D; // coord_out

    char* ws = (char*)d_ws;
    ushort* w1b  = (ushort*)(ws + WS_W1);
    ushort* w2b  = (ushort*)(ws + WS_W2);
    ushort* wc1b = (ushort*)(ws + WS_WC1);
    ushort* wn1b = (ushort*)(ws + WS_WN1);
    ushort* wn2b = (ushort*)(ws + WS_WN2);
    int* cnt  = (int*)(ws + WS_CNT);
    int* cur  = (int*)(ws + WS_CUR);
    int* perm = (int*)(ws + WS_PERM);
    ushort* uArr = (ushort*)(ws + WS_U);
    ushort* vArr = (ushort*)(ws + WS_V);
    ushort* pArr = (ushort*)(ws + WS_P);

    hipMemsetAsync(cnt, 0, N_NODES * sizeof(int), stream);
    prep2<<<(N_EDGES + 255) / 256, 256, 0, stream>>>(We1, We2, Wc1, Wn1, Wn2, coord, eidx,
                                                     w1b, w2b, wc1b, wn1b, wn2b, cout, cnt, hout);
    scan_k<<<1, 1024, 0, stream>>>(cnt, cur);
    uvp_scatter_k<<<NNT64 + NSCAT, 256, 0, stream>>>(
        h, w1b, wn1b, be1, bn1, uArr, vArr, pArr, eidx, cur, perm);
    egcl_edge<<<NBLK4, TPB, 0, stream>>>(uArr, vArr, eidx, perm, coord,
                                         w2b, wc1b, We1, be2, bc1, Wc2,
                                         hout, cout);
    egcl_node<<<NNT64, 256, 0, stream>>>(h, wn1b, wn2b, pArr, bn2, hout);
}

// Round 17
// 304.025 us; speedup vs baseline: 1.2537x; 1.0117x over previous
//
#include <hip/hip_runtime.h>

#define N_NODES 20000
#define N_EDGES 640000
#define D 128
#define H 128

#define EB    64                 // edges per tile (edge kernel)
#define TPB   256                // 4 waves (edge kernel)
#define NBLK4 1024               // edge blocks (4/CU), strided tile schedule
#define NTILE (N_EDGES / EB)     // 10000
#define EBN   64                 // rows per tile (node/uvp kernels)
#define NNT64 ((N_NODES + EBN - 1) / EBN)  // 313
#define NSCAT ((N_EDGES + 255) / 256)      // 2500 scatter blocks
#define ST    136                // bf16 tile row stride; 272B % 128 = 16

// ---- workspace layout (bytes) ----
#define WS_W1   0                // We1[:, :256] bf16 [128][256]
#define WS_W2   65536            // We2 bf16 [128][128]
#define WS_WC1  98304            // Wc1 bf16 [128][128]
#define WS_WN1  131072           // Wn1 bf16 [128][256]
#define WS_WN2  196608           // Wn2 bf16 [128][128]
#define WS_CNT  229376           // int[20000]
#define WS_CUR  309376           // int[20000]
#define WS_PERM 389376           // int[640000]
#define WS_U    2949376          // u bf16 [20000][128]
#define WS_V    8069376          // v bf16 [20000][128]
#define WS_P    13189376         // p bf16 [20000][128]

typedef short bf16x8 __attribute__((ext_vector_type(8)));
typedef float f32x4  __attribute__((ext_vector_type(4)));

__device__ __forceinline__ float silu_f(float x) {
    return x * __builtin_amdgcn_rcpf(1.0f + __expf(-x));
}
__device__ __forceinline__ ushort f2b(float f) {          // f32 -> bf16 RNE (scalar)
    union { float f; unsigned int u; } v; v.f = f;
    return (ushort)((v.u + 0x7FFF + ((v.u >> 16) & 1)) >> 16);
}
__device__ __forceinline__ float b2f(ushort s) {
    union { unsigned int u; float f; } v; v.u = ((unsigned int)s) << 16; return v.f;
}
// packed f32 pair -> 2xbf16 in one u32 (HW RNE)
__device__ __forceinline__ unsigned f2b2(float lo, float hi) {
    unsigned r;
    asm("v_cvt_pk_bf16_f32 %0, %1, %2" : "=v"(r) : "v"(lo), "v"(hi));
    return r;
}

// LDS-only barrier: orders ds ops across the workgroup but does NOT drain
// vmcnt — register-destined global loads stay in flight across it.
__device__ __forceinline__ void bar_lds() {
    asm volatile("s_waitcnt lgkmcnt(0)" ::: "memory");
    __builtin_amdgcn_s_barrier();
    asm volatile("" ::: "memory");
}

// one K=32 chunk with register-resident B: acc[4][2] += A[64 x 32] @ Breg
__device__ __forceinline__ void gemm_chunk_rw(const ushort* Ab, int kc0,
                                              const bf16x8 b[2], f32x4 acc[4][2],
                                              int eg, int lane)
{
    const int r = lane & 15, g = lane >> 4;
    bf16x8 a[4];
    #pragma unroll
    for (int mt = 0; mt < 4; ++mt)
        a[mt] = *(const bf16x8*)&Ab[(eg * 64 + mt * 16 + r) * ST + kc0 + g * 8];
    #pragma unroll
    for (int mt = 0; mt < 4; ++mt)
        #pragma unroll
        for (int nt = 0; nt < 2; ++nt)
            acc[mt][nt] = __builtin_amdgcn_mfma_f32_16x16x32_bf16(a[mt], b[nt], acc[mt][nt], 0, 0, 0);
}

__device__ __forceinline__ void zero_acc8(f32x4 acc[4][2]) {
    #pragma unroll
    for (int mt = 0; mt < 4; ++mt)
        #pragma unroll
        for (int nt = 0; nt < 2; ++nt)
            acc[mt][nt] = (f32x4){0.f, 0.f, 0.f, 0.f};
}

// pk-convert epilogue (edge kernel, eg==0)
__device__ __forceinline__ void epi_silu8_pk(f32x4 acc[4][2], const float* bias,
                                             ushort* out, int eg, int cg, int lane) {
    const int r = lane & 15, g = lane >> 4;
    #pragma unroll
    for (int nt = 0; nt < 2; ++nt) {
        int o = cg * 32 + nt * 16 + r;
        float bo = bias[o];
        #pragma unroll
        for (int mt = 0; mt < 4; ++mt) {
            int e = eg * 64 + mt * 16 + g * 4;
            unsigned p01 = f2b2(silu_f(acc[mt][nt][0] + bo), silu_f(acc[mt][nt][1] + bo));
            unsigned p23 = f2b2(silu_f(acc[mt][nt][2] + bo), silu_f(acc[mt][nt][3] + bo));
            out[(e + 0) * ST + o] = (ushort)p01;
            out[(e + 1) * ST + o] = (ushort)(p01 >> 16);
            out[(e + 2) * ST + o] = (ushort)p23;
            out[(e + 3) * ST + o] = (ushort)(p23 >> 16);
        }
    }
}

// ---------------- prep: weight bf16 conversion + cout copy + histogram + hout zero ----------------
__global__ void prep2(const float* __restrict__ We1, const float* __restrict__ We2,
                      const float* __restrict__ Wc1, const float* __restrict__ Wn1,
                      const float* __restrict__ Wn2, const float* __restrict__ coordp,
                      const int* __restrict__ eidx,
                      ushort* w1, ushort* w2, ushort* wc1, ushort* wn1, ushort* wn2,
                      float* cout, int* cnt, float* hout)
{
    int idx = blockIdx.x * 256 + threadIdx.x;
    if (idx < N_EDGES) {
        // hout zero: 640000 threads x float4 == N_NODES*D floats exactly
        *(float4*)&hout[(size_t)idx * 4] = (float4){0.f, 0.f, 0.f, 0.f};
        atomicAdd(&cnt[eidx[idx]], 1);
    }
    int j = idx;
    if (j < 32768) { w1[j] = f2b(We1[(j >> 8) * 257 + (j & 255)]); return; }
    j -= 32768;
    if (j < 16384) { w2[j] = f2b(We2[j]); return; }
    j -= 16384;
    if (j < 16384) { wc1[j] = f2b(Wc1[j]); return; }
    j -= 16384;
    if (j < 32768) { wn1[j] = f2b(Wn1[j]); return; }
    j -= 32768;
    if (j < 16384) { wn2[j] = f2b(Wn2[j]); return; }
    j -= 16384;
    if (j < N_NODES * 3) cout[j] = coordp[j];
}

// ---------------- counting sort: raking exclusive scan (1 block, 2 barriers) ----------------
// Thread t serially prefixes elements [t*20, t*20+20) in registers (fully
// unrolled), then a 64-lane shfl scan of thread totals + 16-wide cross-wave
// scan. Replaces the 20-pass version (~100 barriers -> 2).
__global__ __launch_bounds__(1024)
void scan_k(const int* __restrict__ cnt, int* __restrict__ cur) {
    __shared__ int wsum[16];
    const int t = threadIdx.x, lane = t & 63, wid = t >> 6;
    const int base = t * 20;
    int loc[20];
    int sum = 0;
    #pragma unroll
    for (int i = 0; i < 20; ++i) {
        int idx = base + i;
        int v = (idx < N_NODES) ? cnt[idx] : 0;
        loc[i] = sum;                 // exclusive-within-thread prefix
        sum += v;
    }
    int s = sum;                      // inclusive scan of thread totals (wave)
    #pragma unroll
    for (int d = 1; d < 64; d <<= 1) {
        int x = __shfl_up(s, d);
        if (lane >= d) s += x;
    }
    if (lane == 63) wsum[wid] = s;
    __syncthreads();
    if (wid == 0) {
        int ws = (lane < 16) ? wsum[lane] : 0;
        #pragma unroll
        for (int d = 1; d < 16; d <<= 1) {
            int x = __shfl_up(ws, d);
            if (lane >= d) ws += x;
        }
        if (lane < 16) wsum[lane] = ws;
    }
    __syncthreads();
    const int off = (wid > 0 ? wsum[wid - 1] : 0) + (s - sum);
    #pragma unroll
    for (int i = 0; i < 20; ++i) {
        int idx = base + i;
        if (idx < N_NODES) cur[idx] = off + loc[i];
    }
}

// ---------------- merged: uvp precompute (blocks < NNT64) + sort scatter ----------------
__global__ __launch_bounds__(256, 2)
void uvp_scatter_k(const float* __restrict__ h,
                   const ushort* __restrict__ w1b, const ushort* __restrict__ wn1b,
                   const float* __restrict__ be1, const float* __restrict__ bn1,
                   ushort* __restrict__ u, ushort* __restrict__ v, ushort* __restrict__ p,
                   const int* __restrict__ eidx, int* cur, int* perm)
{
    const int tid = threadIdx.x;
    if (blockIdx.x >= NNT64) {              // ---- scatter part ----
        int e = (blockIdx.x - NNT64) * 256 + tid;
        if (e < N_EDGES) {
            int pp = atomicAdd(&cur[eidx[e]], 1);
            perm[pp] = e;
        }
        return;
    }
    // ---- uvp part ----
    __shared__ __align__(16) ushort hs[EBN * ST];
    __shared__ float b1s[H], bn1s[H];

    const int lane = tid & 63, wv = tid >> 6;
    const int cg = wv & 3;
    const int r = lane & 15, g = lane >> 4;
    const int n0 = blockIdx.x * EBN;

    if (tid < 128) b1s[tid] = be1[tid];
    else if (tid < 256) bn1s[tid - 128] = bn1[tid - 128];

    bf16x8 wa[4][2], wb[4][2], wn[4][2];
    {
        const int c0 = cg * 32 + r, c1c = c0 + 16;
        #pragma unroll
        for (int kc = 0; kc < 4; ++kc) {
            wa[kc][0] = *(const bf16x8*)&w1b [c0  * 256 +       kc * 32 + g * 8];
            wa[kc][1] = *(const bf16x8*)&w1b [c1c * 256 +       kc * 32 + g * 8];
            wb[kc][0] = *(const bf16x8*)&w1b [c0  * 256 + 128 + kc * 32 + g * 8];
            wb[kc][1] = *(const bf16x8*)&w1b [c1c * 256 + 128 + kc * 32 + g * 8];
            wn[kc][0] = *(const bf16x8*)&wn1b[c0  * 256 +       kc * 32 + g * 8];
            wn[kc][1] = *(const bf16x8*)&wn1b[c1c * 256 +       kc * 32 + g * 8];
        }
    }
    #pragma unroll
    for (int it = 0; it < 8; ++it) {
        int idx = tid + it * 256;
        int e = idx >> 5, c = idx & 31;
        int n = n0 + e; if (n >= N_NODES) n = 0;
        float4 vv = *(const float4*)&h[(size_t)n * D + c * 4];
        ushort4 pk; pk.x = f2b(vv.x); pk.y = f2b(vv.y); pk.z = f2b(vv.z); pk.w = f2b(vv.w);
        *(ushort4*)&hs[e * ST + c * 4] = pk;
    }
    __syncthreads();

    f32x4 acc[4][2];
    zero_acc8(acc);
    #pragma unroll
    for (int kc = 0; kc < 4; ++kc) gemm_chunk_rw(hs, kc * 32, wa[kc], acc, 0, lane);
    #pragma unroll
    for (int nt = 0; nt < 2; ++nt) {
        int o = cg * 32 + nt * 16 + r;
        float bo = b1s[o];
        #pragma unroll
        for (int mt = 0; mt < 4; ++mt)
            #pragma unroll
            for (int j = 0; j < 4; ++j) {
                int n = n0 + mt * 16 + g * 4 + j;
                if (n < N_NODES) u[(size_t)n * H + o] = f2b(acc[mt][nt][j] + bo);
            }
    }
    zero_acc8(acc);
    #pragma unroll
    for (int kc = 0; kc < 4; ++kc) gemm_chunk_rw(hs, kc * 32, wb[kc], acc, 0, lane);
    #pragma unroll
    for (int nt = 0; nt < 2; ++nt) {
        int o = cg * 32 + nt * 16 + r;
        #pragma unroll
        for (int mt = 0; mt < 4; ++mt)
            #pragma unroll
            for (int j = 0; j < 4; ++j) {
                int n = n0 + mt * 16 + g * 4 + j;
                if (n < N_NODES) v[(size_t)n * H + o] = f2b(acc[mt][nt][j]);
            }
    }
    zero_acc8(acc);
    #pragma unroll
    for (int kc = 0; kc < 4; ++kc) gemm_chunk_rw(hs, kc * 32, wn[kc], acc, 0, lane);
    #pragma unroll
    for (int nt = 0; nt < 2; ++nt) {
        int o = cg * 32 + nt * 16 + r;
        float bo = bn1s[o];
        #pragma unroll
        for (int mt = 0; mt < 4; ++mt)
            #pragma unroll
            for (int j = 0; j < 4; ++j) {
                int n = n0 + mt * 16 + g * 4 + j;
                if (n < N_NODES) p[(size_t)n * H + o] = f2b(acc[mt][nt][j] + bo);
            }
    }
}

// ---------------- fused edge kernel (64-edge tiles, 4 blocks/CU, VGPR cap 128) ----------------
// launch_bounds 2nd arg empirical rule on this hipcc: cap = 256/arg VGPRs
// (arg=4 -> 64-reg cap -> spills; arg=2 -> 128-reg cap, fits ~108 live set).
// Occupancy here is LDS-limited: 4 x 40704 B <= 160 KiB -> 4 blocks/CU.
__global__ __launch_bounds__(TPB, 2)
void egcl_edge(const ushort* __restrict__ u, const ushort* __restrict__ v,
               const int* __restrict__ eidx, const int* __restrict__ perm,
               const float* __restrict__ coordp,
               const ushort* __restrict__ w2b, const ushort* __restrict__ wc1b,
               const float* __restrict__ We1,
               const float* __restrict__ be2, const float* __restrict__ bc1,
               const float* __restrict__ Wc2,
               float* __restrict__ agg, float* __restrict__ coord_out)
{
    __shared__ __align__(16) ushort t1[EB * ST];          // 17408 B
    __shared__ __align__(16) ushort ef[EB * ST];          // 17408 B
    __shared__ int   srcs_s[2][EB];                       // 512 B
    __shared__ int   dsts_s[EB];                          // 256 B (single buffer)
    __shared__ float radial_s[2][EB];                     // 512 B
    __shared__ float cdx_s[2][EB], cdy_s[2][EB], cdz_s[2][EB]; // 1536 B
    __shared__ float wcop[4][EB];                         // 1024 B
    __shared__ float b2s[H], bc1s[H], wc2s[H], w256s[H];  // 2048 B  => total 40704 B

    const int tid = threadIdx.x, lane = tid & 63;
    const int cg = tid >> 6;                   // 4 waves = 4 col groups
    const int r = lane & 15, g = lane >> 4;
    const int ce = tid >> 2, cq = tid & 3;     // commit/reduce mapping (64 edges x 4)

    if (tid < 128) { b2s[tid] = be2[tid];  wc2s[tid] = Wc2[tid]; }
    else { int o = tid - 128; bc1s[o] = bc1[o]; w256s[o] = We1[o * 257 + 256]; }

    bf16x8 w2f[4][2], w3f[4][2];
    {
        const int c0 = cg * 32 + r, c1c = c0 + 16;
        #pragma unroll
        for (int kc = 0; kc < 4; ++kc) {
            w2f[kc][0] = *(const bf16x8*)&w2b [c0  * 128 + kc * 32 + g * 8];
            w2f[kc][1] = *(const bf16x8*)&w2b [c1c * 128 + kc * 32 + g * 8];
            w3f[kc][0] = *(const bf16x8*)&wc1b[c0  * 128 + kc * 32 + g * 8];
            w3f[kc][1] = *(const bf16x8*)&wc1b[c1c * 128 + kc * 32 + g * 8];
        }
    }

    // ---- prologue ----
    int t = (int)blockIdx.x;                  // strided: t, t+NBLK4, ...
    int rs = 0, rd = 0;
    float rsx = 0, rsy = 0, rsz = 0, rdx = 0, rdy = 0, rdz = 0;
    if (tid < EB) {
        int e = perm[t * EB + tid];
        int s = eidx[e], d = eidx[N_EDGES + e];
        srcs_s[0][tid] = s; dsts_s[tid] = d;
        float sx = coordp[s * 3], sy = coordp[s * 3 + 1], sz = coordp[s * 3 + 2];
        float dx0 = coordp[d * 3], dy0 = coordp[d * 3 + 1], dz0 = coordp[d * 3 + 2];
        float dx = sx - dx0, dy = sy - dy0, dz = sz - dz0;
        cdx_s[0][tid] = dx; cdy_s[0][tid] = dy; cdz_s[0][tid] = dz;
        radial_s[0][tid] = dx * dx + dy * dy + dz * dz;
    }
    __syncthreads();

    bf16x8 uvr[8];
    {
        const ushort* up = u + (size_t)srcs_s[0][ce] * H + cq * 32;
        const ushort* vp = v + (size_t)dsts_s[ce] * H + cq * 32;
        #pragma unroll
        for (int i = 0; i < 4; ++i) {
            uvr[i]     = *(const bf16x8*)(up + i * 8);
            uvr[4 + i] = *(const bf16x8*)(vp + i * 8);
        }
    }
    if (tid < EB && t + NBLK4 < NTILE) {
        int e = perm[(t + NBLK4) * EB + tid];
        rs = eidx[e]; rd = eidx[N_EDGES + e];
        rsx = coordp[rs * 3]; rsy = coordp[rs * 3 + 1]; rsz = coordp[rs * 3 + 2];
        rdx = coordp[rd * 3]; rdy = coordp[rd * 3 + 1]; rdz = coordp[rd * 3 + 2];
    }

    f32x4 acc[4][2];
    int pb = 0;

    for (; t < NTILE; t += NBLK4) {
        // ---- p0: commit uvr -> t1 = silu(u+v+radial*w256); commit chain -> idx[pb^1]
        {
            float rad = radial_s[pb][ce];
            #pragma unroll
            for (int i = 0; i < 4; ++i) {
                float4 wlo = *(const float4*)&w256s[cq * 32 + i * 8];
                float4 whi = *(const float4*)&w256s[cq * 32 + i * 8 + 4];
                bf16x8 uu = uvr[i], vx = uvr[4 + i];
                float x0 = silu_f(b2f((ushort)uu[0]) + b2f((ushort)vx[0]) + rad * wlo.x);
                float x1 = silu_f(b2f((ushort)uu[1]) + b2f((ushort)vx[1]) + rad * wlo.y);
                float x2 = silu_f(b2f((ushort)uu[2]) + b2f((ushort)vx[2]) + rad * wlo.z);
                float x3 = silu_f(b2f((ushort)uu[3]) + b2f((ushort)vx[3]) + rad * wlo.w);
                float x4 = silu_f(b2f((ushort)uu[4]) + b2f((ushort)vx[4]) + rad * whi.x);
                float x5 = silu_f(b2f((ushort)uu[5]) + b2f((ushort)vx[5]) + rad * whi.y);
                float x6 = silu_f(b2f((ushort)uu[6]) + b2f((ushort)vx[6]) + rad * whi.z);
                float x7 = silu_f(b2f((ushort)uu[7]) + b2f((ushort)vx[7]) + rad * whi.w);
                uint4 pk4;
                pk4.x = f2b2(x0, x1); pk4.y = f2b2(x2, x3);
                pk4.z = f2b2(x4, x5); pk4.w = f2b2(x6, x7);
                *(uint4*)&t1[ce * ST + cq * 32 + i * 8] = pk4;
            }
        }
        if (tid < EB) {
            srcs_s[pb ^ 1][tid] = rs; dsts_s[tid] = rd;
            float dx = rsx - rdx, dy = rsy - rdy, dz = rsz - rdz;
            cdx_s[pb ^ 1][tid] = dx; cdy_s[pb ^ 1][tid] = dy; cdz_s[pb ^ 1][tid] = dz;
            radial_s[pb ^ 1][tid] = dx * dx + dy * dy + dz * dz;
        }
        bar_lds();                                         // A: t1 + idx[pb^1] ready

        // ---- p1: uv(t+N) issue; perm(t+2N); GEMM2 t1 -> ef
        {
            const ushort* up = u + (size_t)srcs_s[pb ^ 1][ce] * H + cq * 32;
            const ushort* vp = v + (size_t)dsts_s[ce] * H + cq * 32;
            #pragma unroll
            for (int i = 0; i < 4; ++i) {
                uvr[i]     = *(const bf16x8*)(up + i * 8);
                uvr[4 + i] = *(const bf16x8*)(vp + i * 8);
            }
        }
        int en = 0;
        if (tid < EB && t + 2 * NBLK4 < NTILE) en = perm[(t + 2 * NBLK4) * EB + tid];
        zero_acc8(acc);
        __builtin_amdgcn_s_setprio(1);
        #pragma unroll
        for (int kc = 0; kc < 4; ++kc) gemm_chunk_rw(t1, kc * 32, w2f[kc], acc, 0, lane);
        __builtin_amdgcn_s_setprio(0);
        epi_silu8_pk(acc, b2s, ef, 0, cg, lane);
        bar_lds();                                         // B: ef ready

        // ---- p2: eidx(t+2N); GEMM3 swapped (W as A, ef as B) -> fused wco; agg scatter
        int rs2 = 0, rd2 = 0;
        if (tid < EB) { rs2 = eidx[en]; rd2 = eidx[N_EDGES + en]; }
        {
            f32x4 acc3[2][4];
            #pragma unroll
            for (int ot = 0; ot < 2; ++ot)
                #pragma unroll
                for (int et = 0; et < 4; ++et)
                    acc3[ot][et] = (f32x4){0.f, 0.f, 0.f, 0.f};
            __builtin_amdgcn_s_setprio(1);
            #pragma unroll
            for (int kc = 0; kc < 4; ++kc) {
                bf16x8 bfr[4];
                #pragma unroll
                for (int et = 0; et < 4; ++et)
                    bfr[et] = *(const bf16x8*)&ef[(et * 16 + r) * ST + kc * 32 + g * 8];
                #pragma unroll
                for (int ot = 0; ot < 2; ++ot)
                    #pragma unroll
                    for (int et = 0; et < 4; ++et)
                        acc3[ot][et] = __builtin_amdgcn_mfma_f32_16x16x32_bf16(
                            w3f[kc][ot], bfr[et], acc3[ot][et], 0, 0, 0);
            }
            __builtin_amdgcn_s_setprio(0);
            // fused epilogue: partial[et] = sum_o silu(acc3+bc1[o]) * wc2[o]
            float partial[4] = {0.f, 0.f, 0.f, 0.f};
            #pragma unroll
            for (int ot = 0; ot < 2; ++ot) {
                int ob = cg * 32 + ot * 16 + g * 4;
                float4 wq = *(const float4*)&wc2s[ob];
                float4 bq = *(const float4*)&bc1s[ob];
                #pragma unroll
                for (int et = 0; et < 4; ++et) {
                    partial[et] += silu_f(acc3[ot][et][0] + bq.x) * wq.x
                                 + silu_f(acc3[ot][et][1] + bq.y) * wq.y
                                 + silu_f(acc3[ot][et][2] + bq.z) * wq.z
                                 + silu_f(acc3[ot][et][3] + bq.w) * wq.w;
                }
            }
            #pragma unroll
            for (int et = 0; et < 4; ++et) {
                float s_ = partial[et];
                s_ += __shfl_xor(s_, 16);
                s_ += __shfl_xor(s_, 32);
                if (g == 0) wcop[cg][et * 16 + r] = s_;
            }
        }
        {   // segmented agg scatter (reads ef, ready since barrier B)
            int o = tid & 127, q = tid >> 7;   // 2 quarters x 32 edges
            int base = q * 32;
            float sum = 0.f;
            int curs = srcs_s[pb][base];
            for (int k = 0; k < 32; ++k) {
                int e = base + k;
                int s = srcs_s[pb][e];
                if (s != curs) {
                    atomicAdd(&agg[(size_t)curs * D + o], sum);
                    sum = 0.f; curs = s;
                }
                sum += b2f(ef[e * ST + o]);
            }
            atomicAdd(&agg[(size_t)curs * D + o], sum);
        }
        bar_lds();                                         // C: wcop ready

        // ---- p3: coord(t+2N) chain; wco sum + coord scatter
        if (tid < EB) {
            rs = rs2; rd = rd2;
            rsx = coordp[rs * 3]; rsy = coordp[rs * 3 + 1]; rsz = coordp[rs * 3 + 2];
            rdx = coordp[rd * 3]; rdy = coordp[rd * 3 + 1]; rdz = coordp[rd * 3 + 2];
        }
        {
            float s_ = wcop[cq][ce];
            s_ += __shfl_down(s_, 2);
            s_ += __shfl_down(s_, 1);
            float wfull = __shfl(s_, lane & ~3);
            if (cq < 3) {
                float cdv = (cq == 0) ? cdx_s[pb][ce] : (cq == 1) ? cdy_s[pb][ce] : cdz_s[pb][ce];
                atomicAdd(&coord_out[(size_t)srcs_s[pb][ce] * 3 + cq], cdv * wfull);
            }
        }
        bar_lds();                                         // E: buffers reusable
        pb ^= 1;
    }
}

// ---------------- node kernel: h_out = h + Wn2 @ silu(p + agg@Wn1b^T) + bn2 ----
__global__ __launch_bounds__(256, 2)
void egcl_node(const float* __restrict__ h,
               const ushort* __restrict__ wn1b, const ushort* __restrict__ wn2b,
               const ushort* __restrict__ pArr, const float* __restrict__ bn2,
               float* __restrict__ hout /* holds agg on entry */)
{
    __shared__ __align__(16) ushort t1[EBN * ST];
    __shared__ __align__(16) ushort t2[EBN * ST];
    __shared__ float b2s[H];

    const int tid = threadIdx.x, lane = tid & 63, wv = tid >> 6;
    const int cg = wv & 3;
    const int r = lane & 15, g = lane >> 4;
    const int n0 = blockIdx.x * EBN;

    if (tid < 128) b2s[tid] = bn2[tid];

    bf16x8 wnb[4][2], w2f[4][2];
    {
        const int c0 = cg * 32 + r, c1c = c0 + 16;
        #pragma unroll
        for (int kc = 0; kc < 4; ++kc) {
            wnb[kc][0] = *(const bf16x8*)&wn1b[c0  * 256 + 128 + kc * 32 + g * 8];
            wnb[kc][1] = *(const bf16x8*)&wn1b[c1c * 256 + 128 + kc * 32 + g * 8];
            w2f[kc][0] = *(const bf16x8*)&wn2b[c0  * 128 + kc * 32 + g * 8];
            w2f[kc][1] = *(const bf16x8*)&wn2b[c1c * 128 + kc * 32 + g * 8];
        }
    }
    #pragma unroll
    for (int it = 0; it < 8; ++it) {
        int idx = tid + it * 256;
        int e = idx >> 5, c = idx & 31;
        int n = n0 + e; if (n >= N_NODES) n = 0;
        float4 vv = *(const float4*)&hout[(size_t)n * D + c * 4];
        ushort4 pk; pk.x = f2b(vv.x); pk.y = f2b(vv.y); pk.z = f2b(vv.z); pk.w = f2b(vv.w);
        *(ushort4*)&t1[e * ST + c * 4] = pk;
    }
    __syncthreads();

    f32x4 acc[4][2];
    zero_acc8(acc);
    #pragma unroll
    for (int kc = 0; kc < 4; ++kc) gemm_chunk_rw(t1, kc * 32, wnb[kc], acc, 0, lane);
    #pragma unroll
    for (int nt = 0; nt < 2; ++nt) {
        int o = cg * 32 + nt * 16 + r;
        #pragma unroll
        for (int mt = 0; mt < 4; ++mt)
            #pragma unroll
            for (int j = 0; j < 4; ++j) {
                int e = mt * 16 + g * 4 + j;
                int n = n0 + e; if (n >= N_NODES) n = 0;
                float x = acc[mt][nt][j] + b2f(pArr[(size_t)n * H + o]);
                t2[e * ST + o] = f2b(silu_f(x));
            }
    }
    __syncthreads();

    zero_acc8(acc);
    #pragma unroll
    for (int kc = 0; kc < 4; ++kc) gemm_chunk_rw(t2, kc * 32, w2f[kc], acc, 0, lane);
    #pragma unroll
    for (int nt = 0; nt < 2; ++nt) {
        int o = cg * 32 + nt * 16 + r;
        float bo = b2s[o];
        #pragma unroll
        for (int mt = 0; mt < 4; ++mt)
            #pragma unroll
            for (int j = 0; j < 4; ++j) {
                int n = n0 + mt * 16 + g * 4 + j;
                if (n < N_NODES)
                    hout[(size_t)n * D + o] = h[(size_t)n * D + o] + acc[mt][nt][j] + bo;
            }
    }
}

extern "C" void kernel_launch(void* const* d_in, const int* in_sizes, int n_in,
                              void* d_out, int out_size, void* d_ws, size_t ws_size,
                              hipStream_t stream)
{
    const float* h     = (const float*)d_in[0];
    const float* coord = (const float*)d_in[1];
    const int*   eidx  = (const int*)d_in[2];
    const float* We1 = (const float*)d_in[3];
    const float* be1 = (const float*)d_in[4];
    const float* We2 = (const float*)d_in[5];
    const float* be2 = (const float*)d_in[6];
    const float* Wn1 = (const float*)d_in[7];
    const float* bn1 = (const float*)d_in[8];
    const float* Wn2 = (const float*)d_in[9];
    const float* bn2 = (const float*)d_in[10];
    const float* Wc1 = (const float*)d_in[11];
    const float* bc1 = (const float*)d_in[12];
    const float* Wc2 = (const float*)d_in[13];

    float* hout = (float*)d_out;                       // h_out; doubles as agg accumulator
    float* cout = (float*)d_out + (size_t)N_NODES * D; // coord_out

    char* ws = (char*)d_ws;
    ushort* w1b  = (ushort*)(ws + WS_W1);
    ushort* w2b  = (ushort*)(ws + WS_W2);
    ushort* wc1b = (ushort*)(ws + WS_WC1);
    ushort* wn1b = (ushort*)(ws + WS_WN1);
    ushort* wn2b = (ushort*)(ws + WS_WN2);
    int* cnt  = (int*)(ws + WS_CNT);
    int* cur  = (int*)(ws + WS_CUR);
    int* perm = (int*)(ws + WS_PERM);
    ushort* uArr = (ushort*)(ws + WS_U);
    ushort* vArr = (ushort*)(ws + WS_V);
    ushort* pArr = (ushort*)(ws + WS_P);

    hipMemsetAsync(cnt, 0, N_NODES * sizeof(int), stream);
    prep2<<<(N_EDGES + 255) / 256, 256, 0, stream>>>(We1, We2, Wc1, Wn1, Wn2, coord, eidx,
                                                     w1b, w2b, wc1b, wn1b, wn2b, cout, cnt, hout);
    scan_k<<<1, 1024, 0, stream>>>(cnt, cur);
    uvp_scatter_k<<<NNT64 + NSCAT, 256, 0, stream>>>(
        h, w1b, wn1b, be1, bn1, uArr, vArr, pArr, eidx, cur, perm);
    egcl_edge<<<NBLK4, TPB, 0, stream>>>(uArr, vArr, eidx, perm, coord,
                                         w2b, wc1b, We1, be2, bc1, Wc2,
                                         hout, cout);
    egcl_node<<<NNT64, 256, 0, stream>>>(h, wn1b, wn2b, pArr, bn2, hout);
}